// Round 1
// baseline (125867.871 us; speedup 1.0000x reference)
//
#include <hip/hip_runtime.h>
#include <math.h>

// Three-body RNN: B=32, S=4096, I=64, H=128, O=64
#define NB 32
#define NS 4096
#define NI 64
#define NH 128
#define NO 64
#define NBLK 256   // 128 i-units x 2 batch-halves
#define RT 256     // threads per recurrence block

// ---------------------------------------------------------------------------
// Kernel 1: input projection  iw[b][t][h] = sum_i u[b][t][i]*W_in[h][i] + b_in[h]
// Stored into the r_out region of d_out (read-then-overwritten by recurrence).
// ---------------------------------------------------------------------------
__global__ __launch_bounds__(256)
void k_input_proj(const float* __restrict__ u, const float* __restrict__ W_in,
                  const float* __restrict__ b_in, float* __restrict__ iw)
{
    const int gid = blockIdx.x * 256 + threadIdx.x;   // < NB*NS*NH = 2^24
    const int h = gid & (NH - 1);
    const int t = (gid >> 7) & (NS - 1);
    const int b = gid >> 19;
    const float* ur = u + ((size_t)b * NS + t) * NI;
    const float* wr = W_in + h * NI;
    float acc = b_in[h];
#pragma unroll
    for (int ii = 0; ii < NI; ++ii) acc = fmaf(ur[ii], wr[ii], acc);
    iw[gid] = acc;   // gid == ((b*NS)+t)*NH + h
}

// ---------------------------------------------------------------------------
// Kernel 2: persistent recurrence. Block bi = (i = bi>>1, bh = bi&1).
// T3[i,:,:] lives in LDS (64 KB). h exchanged via double-buffered global h_buf;
// per-step barrier = 256-slot arrive[] flag array (release store + acquire spin).
// ---------------------------------------------------------------------------
__global__ __launch_bounds__(RT, 1)
void k_recur(const float* __restrict__ T3, const float* __restrict__ bias_t,
             float* __restrict__ r_region,   // [B][S][H]: iw on entry, h on exit
             float* __restrict__ h_last,     // [B][H]
             float* __restrict__ h_buf,      // [2][B][H]
             int* arrive,                    // [NBLK]
             float* __restrict__ gpart)      // [NBLK][64] cross-wave scratch
{
    const int bi  = blockIdx.x;
    const int i   = bi >> 1;
    const int bh  = bi & 1;
    const int tid = threadIdx.x;
    const int bl  = tid & 15;          // local batch
    const int b   = bh * 16 + bl;      // global batch
    const int jg  = tid >> 4;          // j-group 0..15 (8 j's each)
    const int wv  = tid >> 6;          // wave 0..3

    __shared__ float t3s[NH * NH];     // exactly 64 KB
    {
        const float* t3i = T3 + (size_t)i * NH * NH;
        for (int x = tid; x < NH * NH; x += RT) t3s[x] = t3i[x];
    }
    __syncthreads();

    const float bias = bias_t[i];
    float* gp = gpart + bi * 64;

    for (int t = 0; t < NS; ++t) {
        const int p = t & 1;
        const float* hb = h_buf + (size_t)p * (NB * NH) + (size_t)b * NH;

        // own-batch h -> registers (static indices only; L1 serves the redundancy)
        float hreg[NH];
#pragma unroll
        for (int kq = 0; kq < NH / 4; ++kq) {
            const float4 v = reinterpret_cast<const float4*>(hb)[kq];
            hreg[4 * kq + 0] = v.x; hreg[4 * kq + 1] = v.y;
            hreg[4 * kq + 2] = v.z; hreg[4 * kq + 3] = v.w;
        }
        // j-side h values (runtime index -> load, not reg-index)
        float jvv[8];
#pragma unroll
        for (int jj = 0; jj < 8; ++jj) jvv[jj] = hb[jg * 8 + jj];

        float acc = 0.f;
#pragma unroll
        for (int jj = 0; jj < 8; ++jj) {
            const int j = jg * 8 + jj;
            const float4* trow = reinterpret_cast<const float4*>(t3s + j * NH);
            float d0 = 0.f, d1 = 0.f, d2 = 0.f, d3 = 0.f;
#pragma unroll
            for (int kq = 0; kq < NH / 4; ++kq) {
                const float4 tq = trow[kq];   // broadcast LDS read (4 j's/wave)
                d0 = fmaf(tq.x, hreg[4 * kq + 0], d0);
                d1 = fmaf(tq.y, hreg[4 * kq + 1], d1);
                d2 = fmaf(tq.z, hreg[4 * kq + 2], d2);
                d3 = fmaf(tq.w, hreg[4 * kq + 3], d3);
            }
            acc = fmaf(jvv[jj], (d0 + d1) + (d2 + d3), acc);
        }
        // in-wave reduce over the wave's 4 j-groups (lanes bl, bl+16, bl+32, bl+48)
        acc += __shfl_xor(acc, 16);
        acc += __shfl_xor(acc, 32);
        // cross-wave combine via global scratch (LDS is full); intra-block
        // global visibility is ordered by __syncthreads (write-through L1)
        if ((tid & 63) < 16) gp[wv * 16 + bl] = acc;
        __syncthreads();
        if (tid < 16) {
            const float hw = gp[bl] + gp[16 + bl] + gp[32 + bl] + gp[48 + bl];
            const size_t ridx = ((size_t)b * NS + t) * NH + i;
            const float hn = tanhf(hw + bias + r_region[ridx]);
            r_region[ridx] = hn;
            h_buf[(size_t)(p ^ 1) * (NB * NH) + (size_t)b * NH + i] = hn;
            if (t == NS - 1) h_last[(size_t)b * NH + i] = hn;
        }
        __syncthreads();   // drains the h stores (waitcnt before barrier)
        if (tid == 0)
            __hip_atomic_store(&arrive[bi], t + 1, __ATOMIC_RELEASE,
                               __HIP_MEMORY_SCOPE_AGENT);
        // every thread polls one slot; acquire gives cache-inv for next h reads
        while (__hip_atomic_load(&arrive[tid], __ATOMIC_ACQUIRE,
                                 __HIP_MEMORY_SCOPE_AGENT) < t + 1) {}
        __syncthreads();
    }
}

// ---------------------------------------------------------------------------
// Kernel 3: output projection  out[b][s][o] = sum_h r[b][s][h]*W_out[o][h] + b_out[o]
// ---------------------------------------------------------------------------
__global__ __launch_bounds__(256)
void k_out_proj(const float* __restrict__ r, const float* __restrict__ W_out,
                const float* __restrict__ b_out, float* __restrict__ out)
{
    const int gid = blockIdx.x * 256 + threadIdx.x;   // < NB*NS*NO = 2^23
    const int o = gid & (NO - 1);
    const int s = (gid >> 6) & (NS - 1);
    const int b = gid >> 18;
    const float* rr = r + ((size_t)b * NS + s) * NH;
    const float* wr = W_out + o * NH;
    float acc = b_out[o];
#pragma unroll
    for (int h = 0; h < NH; ++h) acc = fmaf(rr[h], wr[h], acc);
    out[gid] = acc;   // gid == ((b*NS)+s)*NO + o
}

// ---------------------------------------------------------------------------
extern "C" void kernel_launch(void* const* d_in, const int* in_sizes, int n_in,
                              void* d_out, int out_size, void* d_ws, size_t ws_size,
                              hipStream_t stream)
{
    const float* u      = (const float*)d_in[0];
    const float* hidden = (const float*)d_in[1];
    const float* W_in   = (const float*)d_in[2];
    const float* b_in   = (const float*)d_in[3];
    const float* T3     = (const float*)d_in[4];
    const float* bias_t = (const float*)d_in[5];
    const float* W_out  = (const float*)d_in[6];
    const float* b_out  = (const float*)d_in[7];

    float* out_f  = (float*)d_out;
    float* out_y  = out_f;                                  // [B][S][O]
    float* out_hl = out_f + (size_t)NB * NS * NO;           // [B][H]
    float* out_r  = out_hl + (size_t)NB * NH;               // [B][S][H]

    float* h_buf  = (float*)d_ws;                                   // 32 KB
    int*   arrive = (int*)((char*)d_ws + 2 * NB * NH * 4);          // 1 KB
    float* gpart  = (float*)((char*)d_ws + 2 * NB * NH * 4 + 1024); // 64 KB

    // reset barrier stamps each call (graph-replay safe), init h0
    hipMemsetAsync(arrive, 0, NBLK * sizeof(int), stream);
    hipMemcpyAsync(h_buf, hidden, NB * NH * sizeof(float),
                   hipMemcpyDeviceToDevice, stream);

    k_input_proj<<<(NB * NS * NH) / 256, 256, 0, stream>>>(u, W_in, b_in, out_r);
    k_recur<<<NBLK, RT, 0, stream>>>(T3, bias_t, out_r, out_hl, h_buf, arrive, gpart);
    k_out_proj<<<(NB * NS * NO) / 256, 256, 0, stream>>>(out_r, W_out, b_out, out_y);
}

// Round 2
// 123775.330 us; speedup vs baseline: 1.0169x; 1.0169x over previous
//
#include <hip/hip_runtime.h>
#include <math.h>

// Three-body RNN: B=32, S=4096, I=64, H=128, O=64
#define NB 32
#define NS 4096
#define NI 64
#define NH 128
#define NO 64
#define NBLK 256   // 128 i-units x 2 batch-halves
#define RT 256     // threads per recurrence block

// h_lds layout: per batch, 16 chunks of 8 floats at stride 12 (bank spread:
// quad index = 3*c mod 8 -> 16 lanes cover 8 bank-quads 2-way = free)
#define CH_STRIDE 12
#define B_STRIDE (16 * CH_STRIDE)   // 192 floats per batch

// ---------------------------------------------------------------------------
// Kernel 1: input projection  iw[b][t][h] = sum_i u[b][t][i]*W_in[h][i] + b_in[h]
// Stored into the r_out region of d_out (read-then-overwritten by recurrence).
// ---------------------------------------------------------------------------
__global__ __launch_bounds__(256)
void k_input_proj(const float* __restrict__ u, const float* __restrict__ W_in,
                  const float* __restrict__ b_in, float* __restrict__ iw)
{
    const int gid = blockIdx.x * 256 + threadIdx.x;   // < NB*NS*NH = 2^24
    const int h = gid & (NH - 1);
    const int t = (gid >> 7) & (NS - 1);
    const int b = gid >> 19;
    const float* ur = u + ((size_t)b * NS + t) * NI;
    const float* wr = W_in + h * NI;
    float acc = b_in[h];
#pragma unroll
    for (int ii = 0; ii < NI; ++ii) acc = fmaf(ur[ii], wr[ii], acc);
    iw[gid] = acc;   // gid == ((b*NS)+t)*NH + h
}

// ---------------------------------------------------------------------------
// Kernel 2: persistent recurrence. Block bi = (i = bi>>1, bh = bi&1).
// T3[i, jg*8..+7, kg*8..+7] lives in 64 REGISTERS per thread (the 8MB tensor
// is register-resident chip-wide). h broadcast via 12KB LDS. Per batch:
// 72 FMA/thread + shfl butterfly reduce. Barrier: 128-slot flag array per
// batch-half, release store + acquire spin (round-1-proven pattern).
// ---------------------------------------------------------------------------
__global__ __launch_bounds__(RT, 1)
void k_recur(const float* __restrict__ T3, const float* __restrict__ bias_t,
             float* __restrict__ r_region,   // [B][S][H]: iw on entry, h on exit
             float* __restrict__ h_last,     // [B][H]
             float* __restrict__ h_buf,      // [2][B][H]
             int* arrive)                    // [2][128]
{
    const int bi  = blockIdx.x;
    const int i   = bi >> 1;
    const int bh  = bi & 1;
    const int tid = threadIdx.x;
    const int jg  = tid >> 4;          // 0..15
    const int kg  = tid & 15;          // 0..15
    const int w   = tid >> 6;          // wave 0..3

    __shared__ float h_lds[16 * B_STRIDE];   // 12 KB
    __shared__ float redbuf[4][16];

    // ---- T3 tile -> registers (static indices only) ----
    float t3r[64];
    {
        const float* base = T3 + (size_t)i * NH * NH + (size_t)(jg * 8) * NH + kg * 8;
#pragma unroll
        for (int jj = 0; jj < 8; ++jj) {
            const float4 a  = *reinterpret_cast<const float4*>(base + jj * NH);
            const float4 b2 = *reinterpret_cast<const float4*>(base + jj * NH + 4);
            t3r[jj * 8 + 0] = a.x;  t3r[jj * 8 + 1] = a.y;
            t3r[jj * 8 + 2] = a.z;  t3r[jj * 8 + 3] = a.w;
            t3r[jj * 8 + 4] = b2.x; t3r[jj * 8 + 5] = b2.y;
            t3r[jj * 8 + 6] = b2.z; t3r[jj * 8 + 7] = b2.w;
        }
    }

    // ---- initial h (t=0) -> LDS ----
    {
        const int b2 = tid >> 4, c = tid & 15;
        const float* src = h_buf + (size_t)(bh * 16 + b2) * NH + c * 8;
        const float4 f0 = *reinterpret_cast<const float4*>(src);
        const float4 f1 = *reinterpret_cast<const float4*>(src + 4);
        float* dst = h_lds + b2 * B_STRIDE + c * CH_STRIDE;
        *reinterpret_cast<float4*>(dst)     = f0;
        *reinterpret_cast<float4*>(dst + 4) = f1;
    }
    __syncthreads();

    const float bias = bias_t[i];
    float iw_cur = 0.f;
    if (tid < 16)
        iw_cur = r_region[((size_t)(bh * 16 + tid) * NS + 0) * NH + i];

    auto loadh = [&](int b, float* hj, float* hk) {
        const float* row = h_lds + b * B_STRIDE;
        const float4 j0 = *reinterpret_cast<const float4*>(row + jg * CH_STRIDE);
        const float4 j1 = *reinterpret_cast<const float4*>(row + jg * CH_STRIDE + 4);
        const float4 k0 = *reinterpret_cast<const float4*>(row + kg * CH_STRIDE);
        const float4 k1 = *reinterpret_cast<const float4*>(row + kg * CH_STRIDE + 4);
        hj[0] = j0.x; hj[1] = j0.y; hj[2] = j0.z; hj[3] = j0.w;
        hj[4] = j1.x; hj[5] = j1.y; hj[6] = j1.z; hj[7] = j1.w;
        hk[0] = k0.x; hk[1] = k0.y; hk[2] = k0.z; hk[3] = k0.w;
        hk[4] = k1.x; hk[5] = k1.y; hk[6] = k1.z; hk[7] = k1.w;
    };
    auto dot = [&](const float* hj, const float* hk) -> float {
        float acc = 0.f;
#pragma unroll
        for (int jj = 0; jj < 8; ++jj) {
            float s0 = 0.f, s1 = 0.f;
#pragma unroll
            for (int kk = 0; kk < 8; kk += 2) {
                s0 = fmaf(t3r[jj * 8 + kk],     hk[kk],     s0);
                s1 = fmaf(t3r[jj * 8 + kk + 1], hk[kk + 1], s1);
            }
            acc = fmaf(hj[jj], s0 + s1, acc);
        }
        return acc;
    };
    auto reduceb = [&](int b, float acc) {
        acc += __shfl_xor(acc, 1);  acc += __shfl_xor(acc, 2);
        acc += __shfl_xor(acc, 4);  acc += __shfl_xor(acc, 8);
        acc += __shfl_xor(acc, 16); acc += __shfl_xor(acc, 32);
        if ((tid & 63) == b) redbuf[w][b] = acc;
    };

    float hjA[8], hkA[8], hjB[8], hkB[8];

    for (int t = 0; t < NS; ++t) {
        // ---- compute phase: software-pipelined over 16 batches ----
        loadh(0, hjA, hkA);
#pragma unroll
        for (int bp = 0; bp < 8; ++bp) {
            const int b0 = 2 * bp, b1 = 2 * bp + 1;
            loadh(b1, hjB, hkB);
            reduceb(b0, dot(hjA, hkA));
            if (b1 + 1 < 16) loadh(b1 + 1, hjA, hkA);
            reduceb(b1, dot(hjB, hkB));
        }
        __syncthreads();

        // ---- finalize: 16 threads, one batch each ----
        if (tid < 16) {
            const float s = redbuf[0][tid] + redbuf[1][tid]
                          + redbuf[2][tid] + redbuf[3][tid];
            const float hn = tanhf(s + bias + iw_cur);
            const size_t ridx = ((size_t)(bh * 16 + tid) * NS + t) * NH + i;
            r_region[ridx] = hn;
            h_buf[(size_t)((t + 1) & 1) * (NB * NH)
                  + (size_t)(bh * 16 + tid) * NH + i] = hn;
            if (t == NS - 1) h_last[(size_t)(bh * 16 + tid) * NH + i] = hn;
            // prefetch next step's iw (in flight across barrier+readback)
            iw_cur = (t + 1 < NS) ? r_region[ridx + NH] : 0.f;
        }
        __syncthreads();   // drains h stores before release; redbuf reads done

        if (t + 1 < NS) {
            if (tid == 0)
                __hip_atomic_store(&arrive[bh * 128 + i], t + 1,
                                   __ATOMIC_RELEASE, __HIP_MEMORY_SCOPE_AGENT);
            while (__hip_atomic_load(&arrive[bh * 128 + (tid & 127)],
                                     __ATOMIC_ACQUIRE,
                                     __HIP_MEMORY_SCOPE_AGENT) < t + 1) {}
            __syncthreads();
            // ---- readback h_{t+1} -> LDS ----
            const int b2 = tid >> 4, c = tid & 15;
            const float* src = h_buf + (size_t)((t + 1) & 1) * (NB * NH)
                             + (size_t)(bh * 16 + b2) * NH + c * 8;
            const float4 f0 = *reinterpret_cast<const float4*>(src);
            const float4 f1 = *reinterpret_cast<const float4*>(src + 4);
            float* dst = h_lds + b2 * B_STRIDE + c * CH_STRIDE;
            *reinterpret_cast<float4*>(dst)     = f0;
            *reinterpret_cast<float4*>(dst + 4) = f1;
            __syncthreads();
        }
    }
}

// ---------------------------------------------------------------------------
// Kernel 3: output projection  out[b][s][o] = sum_h r[b][s][h]*W_out[o][h] + b_out[o]
// ---------------------------------------------------------------------------
__global__ __launch_bounds__(256)
void k_out_proj(const float* __restrict__ r, const float* __restrict__ W_out,
                const float* __restrict__ b_out, float* __restrict__ out)
{
    const int gid = blockIdx.x * 256 + threadIdx.x;   // < NB*NS*NO = 2^23
    const int o = gid & (NO - 1);
    const int s = (gid >> 6) & (NS - 1);
    const int b = gid >> 18;
    const float* rr = r + ((size_t)b * NS + s) * NH;
    const float* wr = W_out + o * NH;
    float acc = b_out[o];
#pragma unroll
    for (int h = 0; h < NH; ++h) acc = fmaf(rr[h], wr[h], acc);
    out[gid] = acc;   // gid == ((b*NS)+s)*NO + o
}

// ---------------------------------------------------------------------------
extern "C" void kernel_launch(void* const* d_in, const int* in_sizes, int n_in,
                              void* d_out, int out_size, void* d_ws, size_t ws_size,
                              hipStream_t stream)
{
    const float* u      = (const float*)d_in[0];
    const float* hidden = (const float*)d_in[1];
    const float* W_in   = (const float*)d_in[2];
    const float* b_in   = (const float*)d_in[3];
    const float* T3     = (const float*)d_in[4];
    const float* bias_t = (const float*)d_in[5];
    const float* W_out  = (const float*)d_in[6];
    const float* b_out  = (const float*)d_in[7];

    float* out_f  = (float*)d_out;
    float* out_y  = out_f;                                  // [B][S][O]
    float* out_hl = out_f + (size_t)NB * NS * NO;           // [B][H]
    float* out_r  = out_hl + (size_t)NB * NH;               // [B][S][H]

    float* h_buf  = (float*)d_ws;                                   // 32 KB
    int*   arrive = (int*)((char*)d_ws + 2 * NB * NH * 4);          // 1 KB

    // reset barrier stamps each call (graph-replay safe), init h0
    hipMemsetAsync(arrive, 0, NBLK * sizeof(int), stream);
    hipMemcpyAsync(h_buf, hidden, NB * NH * sizeof(float),
                   hipMemcpyDeviceToDevice, stream);

    k_input_proj<<<(NB * NS * NH) / 256, 256, 0, stream>>>(u, W_in, b_in, out_r);
    k_recur<<<NBLK, RT, 0, stream>>>(T3, bias_t, out_r, out_hl, h_buf, arrive);
    k_out_proj<<<(NB * NS * NO) / 256, 256, 0, stream>>>(out_r, W_out, b_out, out_y);
}

// Round 3
// 64915.643 us; speedup vs baseline: 1.9389x; 1.9067x over previous
//
#include <hip/hip_runtime.h>
#include <math.h>
#include <stdint.h>

// Three-body RNN: B=32, S=4096, I=64, H=128, O=64
#define NB 32
#define NS 4096
#define NI 64
#define NH 128
#define NO 64
#define RT 256

// h_lds layout: per batch, 16 chunks of 8 floats at stride 12 floats
// (quad index = 3*c mod 8 -> 2-way bank aliasing only = free; verified
// round 2: SQ_LDS_BANK_CONFLICT == 0)
#define CH_STRIDE 12
#define B_STRIDE (16 * CH_STRIDE)   // 192 floats per batch

typedef float f4 __attribute__((ext_vector_type(4)));

// ---------------------------------------------------------------------------
// Kernel 1: input projection  iw[b][t][h] = sum_i u[b][t][i]*W_in[h][i] + b_in[h]
// Stored into the r_out region of d_out (read-then-overwritten by recurrence).
// ---------------------------------------------------------------------------
__global__ __launch_bounds__(256)
void k_input_proj(const float* __restrict__ u, const float* __restrict__ W_in,
                  const float* __restrict__ b_in, float* __restrict__ iw)
{
    const int gid = blockIdx.x * 256 + threadIdx.x;   // < NB*NS*NH = 2^24
    const int h = gid & (NH - 1);
    const int t = (gid >> 7) & (NS - 1);
    const int b = gid >> 19;
    const float* ur = u + ((size_t)b * NS + t) * NI;
    const float* wr = W_in + h * NI;
    float acc = b_in[h];
#pragma unroll
    for (int ii = 0; ii < NI; ++ii) acc = fmaf(ur[ii], wr[ii], acc);
    iw[gid] = acc;   // gid == ((b*NS)+t)*NH + h
}

// ---------------------------------------------------------------------------
// Kernel 1b: init epoch-packed h-exchange buffer, parity 0 = (h0, epoch 0).
// (Parity-1 slots were memset to 0xFF: epoch 0xFFFFFFFF never matches.)
// ---------------------------------------------------------------------------
__global__ __launch_bounds__(256)
void k_init_hex(const float* __restrict__ hidden, uint64_t* __restrict__ hex)
{
    const int gid = blockIdx.x * 256 + threadIdx.x;   // < NB*NH = 4096
    hex[gid] = (uint64_t)__float_as_uint(hidden[gid]);  // epoch 0 in hi bits
}

// ---------------------------------------------------------------------------
// Kernel 2: persistent recurrence. Block bi = (i = bi>>1, bh = bi&1).
// T3[i, jg*8..+7, kg*8..+7] in 16 f4 REGISTERS/thread (literal indices only,
// no lambdas / address-taken arrays -> must stay in VGPRs).
// h exchange: hex[par][b][i] holds (epoch<<32)|float_bits, relaxed agent-scope
// 8B atomics. Reader thread (b2,c) polls its 64B line (8 entries) until all
// epochs == t: data+flag fused, one LLC round trip, no fences.
// Parity double-buffer makes writer overrun impossible (writer of step t+2
// needs h_{t+1} of ALL i, which needs every block to have consumed h_t).
// ---------------------------------------------------------------------------
__global__ __launch_bounds__(RT, 1)
void k_recur(const float* __restrict__ T3, const float* __restrict__ bias_t,
             float* __restrict__ r_region,   // [B][S][H]: iw on entry, h on exit
             float* __restrict__ h_last,     // [B][H]
             uint64_t* hex)                  // [2][B][H] epoch-packed
{
    const int bi  = blockIdx.x;
    const int i   = bi >> 1;
    const int bh  = bi & 1;
    const int B0  = bh * 16;
    const int tid = threadIdx.x;
    const int jg  = tid >> 4;          // 0..15 (also b2 for exchange)
    const int kg  = tid & 15;          // 0..15 (also c  for exchange)
    const int w   = tid >> 6;          // wave 0..3

    __shared__ float h_lds[16 * B_STRIDE];   // 12 KB
    __shared__ float redbuf[4][16];

    // ---- T3 tile -> registers (literal indices, no address taken) ----
    f4 t3v[16];
    {
        const float* base = T3 + (size_t)i * NH * NH + (size_t)(jg * 8) * NH + kg * 8;
#pragma unroll
        for (int jj = 0; jj < 8; ++jj) {
            t3v[2 * jj]     = *reinterpret_cast<const f4*>(base + jj * NH);
            t3v[2 * jj + 1] = *reinterpret_cast<const f4*>(base + jj * NH + 4);
        }
    }

    const float bias = bias_t[i];
    float iw_cur = 0.f;
    if (tid < 16)
        iw_cur = r_region[((size_t)(B0 + tid) * NS + 0) * NH + i];

    for (int t = 0; t < NS; ++t) {
        // ---- poll + readback h_t (thread (jg,kg) owns one 64B line) ----
        {
            const uint64_t* src = hex + ((size_t)(t & 1) * NB + (B0 + jg)) * NH + kg * 8;
            uint64_t v0, v1, v2, v3, v4, v5, v6, v7;
            const uint32_t et = (uint32_t)t;
            for (;;) {
                v0 = __hip_atomic_load(src + 0, __ATOMIC_RELAXED, __HIP_MEMORY_SCOPE_AGENT);
                v1 = __hip_atomic_load(src + 1, __ATOMIC_RELAXED, __HIP_MEMORY_SCOPE_AGENT);
                v2 = __hip_atomic_load(src + 2, __ATOMIC_RELAXED, __HIP_MEMORY_SCOPE_AGENT);
                v3 = __hip_atomic_load(src + 3, __ATOMIC_RELAXED, __HIP_MEMORY_SCOPE_AGENT);
                v4 = __hip_atomic_load(src + 4, __ATOMIC_RELAXED, __HIP_MEMORY_SCOPE_AGENT);
                v5 = __hip_atomic_load(src + 5, __ATOMIC_RELAXED, __HIP_MEMORY_SCOPE_AGENT);
                v6 = __hip_atomic_load(src + 6, __ATOMIC_RELAXED, __HIP_MEMORY_SCOPE_AGENT);
                v7 = __hip_atomic_load(src + 7, __ATOMIC_RELAXED, __HIP_MEMORY_SCOPE_AGENT);
                if ((uint32_t)(v0 >> 32) == et && (uint32_t)(v1 >> 32) == et &&
                    (uint32_t)(v2 >> 32) == et && (uint32_t)(v3 >> 32) == et &&
                    (uint32_t)(v4 >> 32) == et && (uint32_t)(v5 >> 32) == et &&
                    (uint32_t)(v6 >> 32) == et && (uint32_t)(v7 >> 32) == et)
                    break;
            }
            float* dst = h_lds + jg * B_STRIDE + kg * CH_STRIDE;
            f4 lo, hi;
            lo[0] = __uint_as_float((uint32_t)v0); lo[1] = __uint_as_float((uint32_t)v1);
            lo[2] = __uint_as_float((uint32_t)v2); lo[3] = __uint_as_float((uint32_t)v3);
            hi[0] = __uint_as_float((uint32_t)v4); hi[1] = __uint_as_float((uint32_t)v5);
            hi[2] = __uint_as_float((uint32_t)v6); hi[3] = __uint_as_float((uint32_t)v7);
            *reinterpret_cast<f4*>(dst)     = lo;
            *reinterpret_cast<f4*>(dst + 4) = hi;
        }
        __syncthreads();

        // ---- compute phase: 16 batches (partial unroll bounds reg pressure) ----
#pragma unroll 4
        for (int b = 0; b < 16; ++b) {
            const float* row = h_lds + b * B_STRIDE;
            const f4 hj0 = *reinterpret_cast<const f4*>(row + jg * CH_STRIDE);
            const f4 hj1 = *reinterpret_cast<const f4*>(row + jg * CH_STRIDE + 4);
            const f4 hk0 = *reinterpret_cast<const f4*>(row + kg * CH_STRIDE);
            const f4 hk1 = *reinterpret_cast<const f4*>(row + kg * CH_STRIDE + 4);
            float acc = 0.f;
#pragma unroll
            for (int jj = 0; jj < 8; ++jj) {
                const f4 tA = t3v[2 * jj];
                const f4 tB = t3v[2 * jj + 1];
                float s0 = 0.f, s1 = 0.f;
                s0 = fmaf(tA[0], hk0[0], s0); s1 = fmaf(tA[1], hk0[1], s1);
                s0 = fmaf(tA[2], hk0[2], s0); s1 = fmaf(tA[3], hk0[3], s1);
                s0 = fmaf(tB[0], hk1[0], s0); s1 = fmaf(tB[1], hk1[1], s1);
                s0 = fmaf(tB[2], hk1[2], s0); s1 = fmaf(tB[3], hk1[3], s1);
                const float hjv = (jj < 4) ? hj0[jj] : hj1[jj - 4];
                acc = fmaf(hjv, s0 + s1, acc);
            }
            acc += __shfl_xor(acc, 1);  acc += __shfl_xor(acc, 2);
            acc += __shfl_xor(acc, 4);  acc += __shfl_xor(acc, 8);
            acc += __shfl_xor(acc, 16); acc += __shfl_xor(acc, 32);
            if ((tid & 63) == b) redbuf[w][b] = acc;
        }
        __syncthreads();

        // ---- finalize: 16 threads, one batch each ----
        if (tid < 16) {
            const int b = B0 + tid;
            const float s = redbuf[0][tid] + redbuf[1][tid]
                          + redbuf[2][tid] + redbuf[3][tid];
            const float hn = tanhf(s + bias + iw_cur);
            // critical-path store first: fused (value, epoch t+1)
            const uint64_t pv = ((uint64_t)(uint32_t)(t + 1) << 32)
                              | (uint64_t)__float_as_uint(hn);
            __hip_atomic_store(hex + ((size_t)((t + 1) & 1) * NB + b) * NH + i, pv,
                               __ATOMIC_RELAXED, __HIP_MEMORY_SCOPE_AGENT);
            const size_t ridx = ((size_t)b * NS + t) * NH + i;
            r_region[ridx] = hn;
            if (t + 1 < NS) iw_cur = r_region[ridx + NH];  // prefetch next iw
            if (t == NS - 1) h_last[(size_t)b * NH + i] = hn;
        }
        // no sync needed here: next poll only writes h_lds (all compute reads
        // completed before the barrier above); redbuf is rewritten only after
        // the next post-readback __syncthreads.
    }
}

// ---------------------------------------------------------------------------
// Kernel 3: output projection  out[b][s][o] = sum_h r[b][s][h]*W_out[o][h] + b_out[o]
// ---------------------------------------------------------------------------
__global__ __launch_bounds__(256)
void k_out_proj(const float* __restrict__ r, const float* __restrict__ W_out,
                const float* __restrict__ b_out, float* __restrict__ out)
{
    const int gid = blockIdx.x * 256 + threadIdx.x;   // < NB*NS*NO = 2^23
    const int o = gid & (NO - 1);
    const int s = (gid >> 6) & (NS - 1);
    const int b = gid >> 18;
    const float* rr = r + ((size_t)b * NS + s) * NH;
    const float* wr = W_out + o * NH;
    float acc = b_out[o];
#pragma unroll
    for (int h = 0; h < NH; ++h) acc = fmaf(rr[h], wr[h], acc);
    out[gid] = acc;   // gid == ((b*NS)+s)*NO + o
}

// ---------------------------------------------------------------------------
extern "C" void kernel_launch(void* const* d_in, const int* in_sizes, int n_in,
                              void* d_out, int out_size, void* d_ws, size_t ws_size,
                              hipStream_t stream)
{
    const float* u      = (const float*)d_in[0];
    const float* hidden = (const float*)d_in[1];
    const float* W_in   = (const float*)d_in[2];
    const float* b_in   = (const float*)d_in[3];
    const float* T3     = (const float*)d_in[4];
    const float* bias_t = (const float*)d_in[5];
    const float* W_out  = (const float*)d_in[6];
    const float* b_out  = (const float*)d_in[7];

    float* out_f  = (float*)d_out;
    float* out_y  = out_f;                                  // [B][S][O]
    float* out_hl = out_f + (size_t)NB * NS * NO;           // [B][H]
    float* out_r  = out_hl + (size_t)NB * NH;               // [B][S][H]

    uint64_t* hex = (uint64_t*)d_ws;                        // [2][B][H] = 64 KB

    // reset exchange buffer every call (graph-replay safe):
    // 0xFF -> parity-1 epochs 0xFFFFFFFF (never match), then fill parity 0.
    hipMemsetAsync(hex, 0xFF, 2 * NB * NH * sizeof(uint64_t), stream);
    k_init_hex<<<(NB * NH) / 256, 256, 0, stream>>>(hidden, hex);

    k_input_proj<<<(NB * NS * NH) / 256, 256, 0, stream>>>(u, W_in, b_in, out_r);
    k_recur<<<2 * NH, RT, 0, stream>>>(T3, bias_t, out_r, out_hl, hex);
    k_out_proj<<<(NB * NS * NO) / 256, 256, 0, stream>>>(out_r, W_out, b_out, out_y);
}